// Round 1
// baseline (5160.876 us; speedup 1.0000x reference)
//
#include <hip/hip_runtime.h>
#include <hip/hip_bf16.h>

// DimeNet++ forward, f32 baseline.
// Sizes fixed by the problem instance.
namespace {
constexpr int E     = 120000;   // edges
constexpr int T     = 800000;   // triplets
constexpr int NN    = 12000;    // nodes
constexpr int H     = 128;      // hidden
constexpr int INTD  = 64;       // int_emb
constexpr int BE    = 8;        // basis_emb
constexpr int R     = 6;        // num_radial
constexpr int SR    = 42;       // num_spherical * num_radial
constexpr int OE    = 256;      // out_emb
constexpr float CUTOFF = 5.0f;
}

__device__ __forceinline__ float silu_f(float x) {
    return x / (1.0f + __expf(-x));
}

// ---------------------------------------------------------------------------
// rbf[E,6] = envelope(d) * sin(freq*d), d = dist/cutoff
// ---------------------------------------------------------------------------
__global__ void k_rbf(const float* __restrict__ dist, const float* __restrict__ freq,
                      float* __restrict__ rbf) {
    int e = blockIdx.x * blockDim.x + threadIdx.x;
    if (e >= E) return;
    float d  = dist[e] * (1.0f / CUTOFF);
    float d2 = d * d;
    float d5 = d2 * d2 * d;
    float env = 1.0f / d - 28.0f * d5 + 48.0f * d5 * d - 21.0f * d5 * d2;
    #pragma unroll
    for (int i = 0; i < R; ++i) {
        rbf[e * R + i] = env * sinf(freq[i] * d);
    }
}

// ---------------------------------------------------------------------------
// Generic row-block GEMM: C[M,NCOL] = act(A[M,K] (.*pre) @ W[K,NCOL] + bias) + post
// Block: 256 threads, ROWS rows. A tile staged in LDS; W streamed (L2-resident).
// M must be divisible by ROWS (true for all call sites here).
// In-place (C==A or C==post) is safe: blocks own disjoint row ranges and
// stage/read before writing.
// ---------------------------------------------------------------------------
template<int K, int NCOL, bool SILU, bool BIAS, bool PRE, bool POST>
__global__ __launch_bounds__(256) void k_gemm(
    const float* __restrict__ A, const float* __restrict__ W,
    const float* __restrict__ bias, const float* __restrict__ pre,
    const float* __restrict__ post, float* __restrict__ C)
{
    constexpr int CG   = NCOL / 4;       // float4 column groups
    constexpr int RG   = 256 / CG;       // row-quad groups
    constexpr int ROWS = RG * 4;
    __shared__ float As[ROWS * K];

    const int tid = threadIdx.x;
    const int r0  = blockIdx.x * ROWS;

    const float4* A4  = reinterpret_cast<const float4*>(A + (size_t)r0 * K);
    float4*       As4 = reinterpret_cast<float4*>(As);
    constexpr int TOT4 = ROWS * K / 4;
    if constexpr (PRE) {
        const float4* P4 = reinterpret_cast<const float4*>(pre + (size_t)r0 * K);
        for (int i = tid; i < TOT4; i += 256) {
            float4 a = A4[i], p = P4[i];
            a.x *= p.x; a.y *= p.y; a.z *= p.z; a.w *= p.w;
            As4[i] = a;
        }
    } else {
        for (int i = tid; i < TOT4; i += 256) As4[i] = A4[i];
    }
    __syncthreads();

    const int cg = tid % CG;
    const int rq = tid / CG;
    const int c0 = cg * 4;

    float acc[4][4];
    if constexpr (BIAS) {
        const float4 bv = *reinterpret_cast<const float4*>(bias + c0);
        #pragma unroll
        for (int r = 0; r < 4; ++r) {
            acc[r][0] = bv.x; acc[r][1] = bv.y; acc[r][2] = bv.z; acc[r][3] = bv.w;
        }
    } else {
        #pragma unroll
        for (int r = 0; r < 4; ++r)
            #pragma unroll
            for (int j = 0; j < 4; ++j) acc[r][j] = 0.0f;
    }

    const float4* W4   = reinterpret_cast<const float4*>(W);
    const float*  Arow = As + rq * 4 * K;
    #pragma unroll 4
    for (int k = 0; k < K; ++k) {
        const float4 wv = W4[k * CG + cg];
        #pragma unroll
        for (int r = 0; r < 4; ++r) {
            const float a = Arow[r * K + k];
            acc[r][0] = fmaf(a, wv.x, acc[r][0]);
            acc[r][1] = fmaf(a, wv.y, acc[r][1]);
            acc[r][2] = fmaf(a, wv.z, acc[r][2]);
            acc[r][3] = fmaf(a, wv.w, acc[r][3]);
        }
    }

    #pragma unroll
    for (int r = 0; r < 4; ++r) {
        const int row = r0 + rq * 4 + r;
        float4 v = make_float4(acc[r][0], acc[r][1], acc[r][2], acc[r][3]);
        if constexpr (SILU) {
            v.x = silu_f(v.x); v.y = silu_f(v.y);
            v.z = silu_f(v.z); v.w = silu_f(v.w);
        }
        if constexpr (POST) {
            const float4 pv = *reinterpret_cast<const float4*>(post + (size_t)row * NCOL + c0);
            v.x += pv.x; v.y += pv.y; v.z += pv.z; v.w += pv.w;
        }
        *reinterpret_cast<float4*>(C + (size_t)row * NCOL + c0) = v;
    }
}

template<int K, int NCOL, bool SILU, bool BIAS, bool PRE, bool POST>
static void gemm(const float* A, const float* W, const float* bias, const float* pre,
                 const float* post, float* C, int M, hipStream_t s)
{
    constexpr int ROWS = (256 / (NCOL / 4)) * 4;
    k_gemm<K, NCOL, SILU, BIAS, PRE, POST><<<M / ROWS, 256, 0, s>>>(A, W, bias, pre, post, C);
}

// ---------------------------------------------------------------------------
// rb[E,H] = (rbf[E,6] @ W1[6,8]) @ W2[8,128]   (tmp recomputed per thread; cheap)
// ---------------------------------------------------------------------------
__global__ __launch_bounds__(256) void k_rb(
    const float* __restrict__ rbf, const float* __restrict__ W1,
    const float* __restrict__ W2, float* __restrict__ rb)
{
    int idx = blockIdx.x * 256 + threadIdx.x;   // over E*H
    int e = idx >> 7;
    int c = idx & (H - 1);
    if (e >= E) return;
    float r6[R];
    #pragma unroll
    for (int i = 0; i < R; ++i) r6[i] = rbf[e * R + i];
    float out = 0.0f;
    #pragma unroll
    for (int j = 0; j < BE; ++j) {
        float tj = 0.0f;
        #pragma unroll
        for (int i = 0; i < R; ++i) tj = fmaf(r6[i], W1[i * BE + j], tj);
        out = fmaf(tj, W2[j * H + c], out);
    }
    rb[idx] = out;
}

// ---------------------------------------------------------------------------
// Triplet kernel: per triplet t
//   sb[64] = (sbf[t,42] @ W1[42,8]) @ W2[8,64]
//   m = xkj_down[idx_kj[t], :] * sb ;  atomicAdd(agg[idx_ji[t], :], m)
// 32 triplets / 256-thread block.
// ---------------------------------------------------------------------------
__global__ __launch_bounds__(256) void k_triplet(
    const float* __restrict__ sbf, const int* __restrict__ idx_kj,
    const int* __restrict__ idx_ji, const float* __restrict__ xkj,
    const float* __restrict__ W1, const float* __restrict__ W2,
    float* __restrict__ agg)
{
    __shared__ float s_sbf[32 * SR];
    __shared__ float s_tmp[32 * BE];
    __shared__ float s_W1[SR * BE];
    __shared__ float s_W2[BE * INTD];

    const int tid = threadIdx.x;
    const int t0  = blockIdx.x * 32;

    for (int i = tid; i < SR * BE; i += 256) s_W1[i] = W1[i];
    for (int i = tid; i < BE * INTD; i += 256) s_W2[i] = W2[i];
    const float* sb0 = sbf + (size_t)t0 * SR;
    for (int i = tid; i < 32 * SR; i += 256) s_sbf[i] = sb0[i];
    __syncthreads();

    // phase 1: tmp[32][8]
    {
        const int tt = tid >> 3, j = tid & 7;
        float s = 0.0f;
        #pragma unroll
        for (int i = 0; i < SR; ++i) s = fmaf(s_sbf[tt * SR + i], s_W1[i * BE + j], s);
        s_tmp[tt * BE + j] = s;
    }
    __syncthreads();

    // phase 2: 8 channels per thread
    const int tt = tid >> 3;
    const int cgc = (tid & 7) * 8;
    const int trip = t0 + tt;
    const int kj = idx_kj[trip];
    const int ji = idx_ji[trip];

    float tmp[BE];
    #pragma unroll
    for (int j = 0; j < BE; ++j) tmp[j] = s_tmp[tt * BE + j];

    const float* gk = xkj + (size_t)kj * INTD + cgc;
    float4 g0 = *reinterpret_cast<const float4*>(gk);
    float4 g1 = *reinterpret_cast<const float4*>(gk + 4);
    float gv[8] = {g0.x, g0.y, g0.z, g0.w, g1.x, g1.y, g1.z, g1.w};

    float* dst = agg + (size_t)ji * INTD + cgc;
    #pragma unroll
    for (int cc = 0; cc < 8; ++cc) {
        float sbv = 0.0f;
        #pragma unroll
        for (int j = 0; j < BE; ++j) sbv = fmaf(tmp[j], s_W2[j * INTD + cgc + cc], sbv);
        unsafeAtomicAdd(dst + cc, sbv * gv[cc]);
    }
}

// ---------------------------------------------------------------------------
// Output-block scatter: g[e,c] = (rbf[e,:] @ Wo_rbf[:,c]) * xe[e,c];
// atomicAdd(nodes[edge_i[e], c], g)
// ---------------------------------------------------------------------------
__global__ __launch_bounds__(256) void k_outscatter(
    const float* __restrict__ rbf, const float* __restrict__ Wrbf,
    const float* __restrict__ xe, const int* __restrict__ edge_i,
    float* __restrict__ nodes)
{
    int idx = blockIdx.x * 256 + threadIdx.x;   // over E*H
    int e = idx >> 7;
    int c = idx & (H - 1);
    if (e >= E) return;
    float g = 0.0f;
    #pragma unroll
    for (int i = 0; i < R; ++i) g = fmaf(rbf[e * R + i], Wrbf[i * H + c], g);
    g *= xe[idx];
    unsafeAtomicAdd(&nodes[(size_t)edge_i[e] * H + c], g);
}

// ---------------------------------------------------------------------------
// P[n] += hN[n,:256] @ Wout[:256]   (one wave per node)
// ---------------------------------------------------------------------------
__global__ __launch_bounds__(256) void k_outdot(
    const float* __restrict__ hN, const float* __restrict__ Wout,
    float* __restrict__ P)
{
    int n = blockIdx.x * 4 + (threadIdx.x >> 6);
    int lane = threadIdx.x & 63;
    float s = 0.0f;
    #pragma unroll
    for (int k = lane; k < OE; k += 64) s = fmaf(hN[(size_t)n * OE + k], Wout[k], s);
    #pragma unroll
    for (int off = 32; off; off >>= 1) s += __shfl_down(s, off);
    if (lane == 0) P[n] += s;
}

// ---------------------------------------------------------------------------
extern "C" void kernel_launch(void* const* d_in, const int* in_sizes, int n_in,
                              void* d_out, int out_size, void* d_ws, size_t ws_size,
                              hipStream_t stream)
{
    (void)in_sizes; (void)n_in; (void)out_size; (void)ws_size;

    const float* x       = (const float*)d_in[0];
    const float* dist    = (const float*)d_in[1];
    const float* freq    = (const float*)d_in[2];
    const float* sbf     = (const float*)d_in[3];
    const int*   idx_kj  = (const int*)d_in[4];
    const int*   idx_ji  = (const int*)d_in[5];
    const int*   edge_i  = (const int*)d_in[6];
    // d_in[7] = num_nodes (compile-time constant NN)
    const float* Wi_rbf1 = (const float*)d_in[8];
    const float* Wi_rbf2 = (const float*)d_in[9];
    const float* Wi_sbf1 = (const float*)d_in[10];
    const float* Wi_sbf2 = (const float*)d_in[11];
    const float* Wi_kj   = (const float*)d_in[12];
    const float* bi_kj   = (const float*)d_in[13];
    const float* Wi_ji   = (const float*)d_in[14];
    const float* bi_ji   = (const float*)d_in[15];
    const float* Wi_down = (const float*)d_in[16];
    const float* Wi_up   = (const float*)d_in[17];
    const float* Wi_res  = (const float*)d_in[18];
    const float* bi_res  = (const float*)d_in[19];
    const float* Wi_lin  = (const float*)d_in[20];
    const float* bi_lin  = (const float*)d_in[21];
    const float* Wo_rbf  = (const float*)d_in[22];
    const float* Wo_up   = (const float*)d_in[23];
    const float* bo_up   = (const float*)d_in[24];
    const float* Wo_lin  = (const float*)d_in[25];
    const float* bo_lin  = (const float*)d_in[26];
    const float* Wo_out  = (const float*)d_in[27];
    float* P = (float*)d_out;

    // workspace carve-up (~402 MB of f32)
    float* w     = (float*)d_ws;
    float* rbf   = w;  w += (size_t)E * R;
    float* xeA   = w;  w += (size_t)E * H;
    float* xeB   = w;  w += (size_t)E * H;
    float* xji   = w;  w += (size_t)E * H;
    float* xkj   = w;  w += (size_t)E * H;
    float* rbt   = w;  w += (size_t)E * H;     // rb, then residual temp
    float* down  = w;  w += (size_t)E * INTD;
    float* agg   = w;  w += (size_t)E * INTD;
    float* nodes = w;  w += (size_t)NN * H;
    float* hN1   = w;  w += (size_t)NN * OE;
    float* hN2   = w;  w += (size_t)NN * OE;

    hipMemsetAsync(d_out, 0, (size_t)NN * sizeof(float), stream);
    k_rbf<<<(E + 255) / 256, 256, 0, stream>>>(dist, freq, rbf);

    auto out_block = [&](int b, const float* xe) {
        hipMemsetAsync(nodes, 0, (size_t)NN * H * sizeof(float), stream);
        k_outscatter<<<E * H / 256, 256, 0, stream>>>(rbf, Wo_rbf + (size_t)b * R * H,
                                                      xe, edge_i, nodes);
        gemm<H, OE, false, true, false, false>(nodes, Wo_up + (size_t)b * H * OE,
                                               bo_up + (size_t)b * OE,
                                               nullptr, nullptr, hN1, NN, stream);
        gemm<OE, OE, true, true, false, false>(hN1, Wo_lin + (size_t)(b * 3 + 0) * OE * OE,
                                               bo_lin + (size_t)(b * 3 + 0) * OE,
                                               nullptr, nullptr, hN2, NN, stream);
        gemm<OE, OE, true, true, false, false>(hN2, Wo_lin + (size_t)(b * 3 + 1) * OE * OE,
                                               bo_lin + (size_t)(b * 3 + 1) * OE,
                                               nullptr, nullptr, hN1, NN, stream);
        gemm<OE, OE, true, true, false, false>(hN1, Wo_lin + (size_t)(b * 3 + 2) * OE * OE,
                                               bo_lin + (size_t)(b * 3 + 2) * OE,
                                               nullptr, nullptr, hN2, NN, stream);
        k_outdot<<<NN / 4, 256, 0, stream>>>(hN2, Wo_out + (size_t)b * OE, P);
    };

    auto interact = [&](int b, const float* xe, float* h) {
        gemm<H, H, true, true, false, false>(xe, Wi_ji + (size_t)b * H * H,
                                             bi_ji + (size_t)b * H,
                                             nullptr, nullptr, xji, E, stream);
        gemm<H, H, true, true, false, false>(xe, Wi_kj + (size_t)b * H * H,
                                             bi_kj + (size_t)b * H,
                                             nullptr, nullptr, xkj, E, stream);
        k_rb<<<E * H / 256, 256, 0, stream>>>(rbf, Wi_rbf1 + (size_t)b * R * BE,
                                              Wi_rbf2 + (size_t)b * BE * H, rbt);
        gemm<H, INTD, true, false, true, false>(xkj, Wi_down + (size_t)b * H * INTD,
                                                nullptr, rbt, nullptr, down, E, stream);
        hipMemsetAsync(agg, 0, (size_t)E * INTD * sizeof(float), stream);
        k_triplet<<<T / 32, 256, 0, stream>>>(sbf, idx_kj, idx_ji, down,
                                              Wi_sbf1 + (size_t)b * SR * BE,
                                              Wi_sbf2 + (size_t)b * BE * INTD, agg);
        gemm<INTD, H, true, false, false, true>(agg, Wi_up + (size_t)b * INTD * H,
                                                nullptr, nullptr, xji, h, E, stream);
        // residual 0 (before skip)
        {
            const float* W0 = Wi_res + ((size_t)(b * 3 + 0) * 2 + 0) * H * H;
            const float* b0 = bi_res + ((size_t)(b * 3 + 0) * 2 + 0) * H;
            const float* W1 = Wi_res + ((size_t)(b * 3 + 0) * 2 + 1) * H * H;
            const float* b1 = bi_res + ((size_t)(b * 3 + 0) * 2 + 1) * H;
            gemm<H, H, true, true, false, false>(h, W0, b0, nullptr, nullptr, rbt, E, stream);
            gemm<H, H, true, true, false, true>(rbt, W1, b1, nullptr, h, h, E, stream);
        }
        // skip: h = silu(h@Wi_lin + b) + xe
        gemm<H, H, true, true, false, true>(h, Wi_lin + (size_t)b * H * H,
                                            bi_lin + (size_t)b * H,
                                            nullptr, xe, h, E, stream);
        // residuals 1,2 (after skip)
        for (int r = 1; r <= 2; ++r) {
            const float* W0 = Wi_res + ((size_t)(b * 3 + r) * 2 + 0) * H * H;
            const float* b0 = bi_res + ((size_t)(b * 3 + r) * 2 + 0) * H;
            const float* W1 = Wi_res + ((size_t)(b * 3 + r) * 2 + 1) * H * H;
            const float* b1 = bi_res + ((size_t)(b * 3 + r) * 2 + 1) * H;
            gemm<H, H, true, true, false, false>(h, W0, b0, nullptr, nullptr, rbt, E, stream);
            gemm<H, H, true, true, false, true>(rbt, W1, b1, nullptr, h, h, E, stream);
        }
    };

    out_block(0, x);
    interact(0, x, xeB);
    out_block(1, xeB);
    interact(1, xeB, xeA);
    out_block(2, xeA);
}

// Round 2
// 3192.163 us; speedup vs baseline: 1.6167x; 1.6167x over previous
//
#include <hip/hip_runtime.h>
#include <hip/hip_bf16.h>

// DimeNet++ forward, f32, CSR-gather version (no float scatter atomics).
namespace {
constexpr int E     = 120000;   // edges
constexpr int T     = 800000;   // triplets
constexpr int NN    = 12000;    // nodes
constexpr int H     = 128;      // hidden
constexpr int INTD  = 64;       // int_emb
constexpr int BE    = 8;        // basis_emb
constexpr int R     = 6;        // num_radial
constexpr int SR    = 42;       // num_spherical * num_radial
constexpr int OE    = 256;      // out_emb
constexpr float CUTOFF = 5.0f;
}

__device__ __forceinline__ float silu_f(float x) {
    return x / (1.0f + __expf(-x));
}

// ---------------------------------------------------------------------------
// rbf[E,6] = envelope(d) * sin(freq*d), d = dist/cutoff
// ---------------------------------------------------------------------------
__global__ void k_rbf(const float* __restrict__ dist, const float* __restrict__ freq,
                      float* __restrict__ rbf) {
    int e = blockIdx.x * blockDim.x + threadIdx.x;
    if (e >= E) return;
    float d  = dist[e] * (1.0f / CUTOFF);
    float d2 = d * d;
    float d5 = d2 * d2 * d;
    float env = 1.0f / d - 28.0f * d5 + 48.0f * d5 * d - 21.0f * d5 * d2;
    #pragma unroll
    for (int i = 0; i < R; ++i) {
        rbf[e * R + i] = env * sinf(freq[i] * d);
    }
}

// ---------------------------------------------------------------------------
// CSR build: count -> scan -> fill  (int atomics only; order within a segment
// is non-deterministic but sums stay within f32 tolerance)
// ---------------------------------------------------------------------------
__global__ void k_count(const int* __restrict__ idx, int n, int* __restrict__ cnt) {
    int i = blockIdx.x * 256 + threadIdx.x;
    if (i < n) atomicAdd(&cnt[idx[i]], 1);
}

// single-block exclusive scan; rs[0..n] row starts; cur[i]=rs[i]. In-place safe
// with cnt==cur (each element read before its owner writes it).
__global__ __launch_bounds__(1024) void k_scan(const int* __restrict__ cnt, int n,
                                               int* __restrict__ rs, int* __restrict__ cur) {
    __shared__ int part[1024];
    const int tid = threadIdx.x;
    const int chunk = (n + 1023) / 1024;
    const int lo = tid * chunk;
    const int hi = min(lo + chunk, n);
    int s = 0;
    for (int i = lo; i < hi; ++i) s += cnt[i];
    part[tid] = s;
    __syncthreads();
    for (int off = 1; off < 1024; off <<= 1) {
        int v = (tid >= off) ? part[tid - off] : 0;
        __syncthreads();
        part[tid] += v;
        __syncthreads();
    }
    int base = (tid == 0) ? 0 : part[tid - 1];
    for (int i = lo; i < hi; ++i) {
        int c = cnt[i];
        rs[i] = base;
        cur[i] = base;
        base += c;
    }
    if (tid == 1023) rs[n] = base;
}

__global__ void k_fill(const int* __restrict__ idx, int n, int* __restrict__ cur,
                       int* __restrict__ perm) {
    int i = blockIdx.x * 256 + threadIdx.x;
    if (i < n) perm[atomicAdd(&cur[idx[i]], 1)] = i;
}

// ---------------------------------------------------------------------------
// Generic row-block GEMM: C[M,NCOL] = act(A[M,K] (.*pre) @ W[K,NCOL] + bias) + post
// 256 threads, ROWS = (256/(NCOL/4))*RPT rows per block. A staged in LDS.
// In-place (C==A or C==post) safe: blocks own disjoint row ranges.
// ---------------------------------------------------------------------------
template<int K, int NCOL, int RPT, bool SILU, bool BIAS, bool PRE, bool POST>
__global__ __launch_bounds__(256) void k_gemm(
    const float* __restrict__ A, const float* __restrict__ W,
    const float* __restrict__ bias, const float* __restrict__ pre,
    const float* __restrict__ post, float* __restrict__ C)
{
    constexpr int CG   = NCOL / 4;       // float4 column groups
    constexpr int RG   = 256 / CG;       // row groups
    constexpr int ROWS = RG * RPT;
    __shared__ float As[ROWS * K];

    const int tid = threadIdx.x;
    const int r0  = blockIdx.x * ROWS;

    const float4* A4  = reinterpret_cast<const float4*>(A + (size_t)r0 * K);
    float4*       As4 = reinterpret_cast<float4*>(As);
    constexpr int TOT4 = ROWS * K / 4;
    if constexpr (PRE) {
        const float4* P4 = reinterpret_cast<const float4*>(pre + (size_t)r0 * K);
        for (int i = tid; i < TOT4; i += 256) {
            float4 a = A4[i], p = P4[i];
            a.x *= p.x; a.y *= p.y; a.z *= p.z; a.w *= p.w;
            As4[i] = a;
        }
    } else {
        for (int i = tid; i < TOT4; i += 256) As4[i] = A4[i];
    }
    __syncthreads();

    const int cg = tid % CG;
    const int rq = tid / CG;
    const int c0 = cg * 4;

    float acc[RPT][4];
    if constexpr (BIAS) {
        const float4 bv = *reinterpret_cast<const float4*>(bias + c0);
        #pragma unroll
        for (int r = 0; r < RPT; ++r) {
            acc[r][0] = bv.x; acc[r][1] = bv.y; acc[r][2] = bv.z; acc[r][3] = bv.w;
        }
    } else {
        #pragma unroll
        for (int r = 0; r < RPT; ++r)
            #pragma unroll
            for (int j = 0; j < 4; ++j) acc[r][j] = 0.0f;
    }

    const float4* W4   = reinterpret_cast<const float4*>(W);
    const float*  Arow = As + rq * RPT * K;
    #pragma unroll 4
    for (int k = 0; k < K; ++k) {
        const float4 wv = W4[k * CG + cg];
        #pragma unroll
        for (int r = 0; r < RPT; ++r) {
            const float a = Arow[r * K + k];
            acc[r][0] = fmaf(a, wv.x, acc[r][0]);
            acc[r][1] = fmaf(a, wv.y, acc[r][1]);
            acc[r][2] = fmaf(a, wv.z, acc[r][2]);
            acc[r][3] = fmaf(a, wv.w, acc[r][3]);
        }
    }

    #pragma unroll
    for (int r = 0; r < RPT; ++r) {
        const int row = r0 + rq * RPT + r;
        float4 v = make_float4(acc[r][0], acc[r][1], acc[r][2], acc[r][3]);
        if constexpr (SILU) {
            v.x = silu_f(v.x); v.y = silu_f(v.y);
            v.z = silu_f(v.z); v.w = silu_f(v.w);
        }
        if constexpr (POST) {
            const float4 pv = *reinterpret_cast<const float4*>(post + (size_t)row * NCOL + c0);
            v.x += pv.x; v.y += pv.y; v.z += pv.z; v.w += pv.w;
        }
        *reinterpret_cast<float4*>(C + (size_t)row * NCOL + c0) = v;
    }
}

template<int K, int NCOL, int RPT, bool SILU, bool BIAS, bool PRE, bool POST>
static void gemm(const float* A, const float* W, const float* bias, const float* pre,
                 const float* post, float* C, int M, hipStream_t s)
{
    constexpr int ROWS = (256 / (NCOL / 4)) * RPT;
    k_gemm<K, NCOL, RPT, SILU, BIAS, PRE, POST><<<M / ROWS, 256, 0, s>>>(A, W, bias, pre, post, C);
}

// ---------------------------------------------------------------------------
// rb[E,H] = (rbf[E,6] @ W1[6,8]) @ W2[8,128]
// ---------------------------------------------------------------------------
__global__ __launch_bounds__(256) void k_rb(
    const float* __restrict__ rbf, const float* __restrict__ W1,
    const float* __restrict__ W2, float* __restrict__ rb)
{
    int idx = blockIdx.x * 256 + threadIdx.x;   // over E*H
    int e = idx >> 7;
    int c = idx & (H - 1);
    if (e >= E) return;
    float r6[R];
    #pragma unroll
    for (int i = 0; i < R; ++i) r6[i] = rbf[e * R + i];
    float out = 0.0f;
    #pragma unroll
    for (int j = 0; j < BE; ++j) {
        float tj = 0.0f;
        #pragma unroll
        for (int i = 0; i < R; ++i) tj = fmaf(r6[i], W1[i * BE + j], tj);
        out = fmaf(tj, W2[j * H + c], out);
    }
    rb[idx] = out;
}

// ---------------------------------------------------------------------------
// tmp_sb[T,8] = sbf[T,42] @ W1[42,8]   (32 triplets / 256-thread block)
// ---------------------------------------------------------------------------
__global__ __launch_bounds__(256) void k_sbfproj(
    const float* __restrict__ sbf, const float* __restrict__ W1,
    float* __restrict__ tmp)
{
    __shared__ float s_sbf[32 * SR];
    __shared__ float s_W1[SR * BE];
    const int tid = threadIdx.x;
    const int t0  = blockIdx.x * 32;
    for (int i = tid; i < SR * BE; i += 256) s_W1[i] = W1[i];
    const float* sb0 = sbf + (size_t)t0 * SR;
    for (int i = tid; i < 32 * SR; i += 256) s_sbf[i] = sb0[i];
    __syncthreads();
    const int tt = tid >> 3, j = tid & 7;
    float s = 0.0f;
    #pragma unroll
    for (int i = 0; i < SR; ++i) s = fmaf(s_sbf[tt * SR + i], s_W1[i * BE + j], s);
    tmp[(size_t)(t0 + tt) * BE + j] = s;
}

// ---------------------------------------------------------------------------
// Fused triplet aggregation + up-projection, one wave per edge:
//   acc[64] = sum over triplets t with idx_ji[t]==e of down[idx_kj[t],:] * (tmp_sb[t]@W2)
//   h[e,:]  = silu(acc @ Wup) + xji[e,:]
// ---------------------------------------------------------------------------
__global__ __launch_bounds__(256) void k_aggup(
    const int* __restrict__ rs, const int* __restrict__ perm,
    const int* __restrict__ idx_kj, const float* __restrict__ tmp_sb,
    const float* __restrict__ down, const float* __restrict__ W2,
    const float* __restrict__ Wup, const float* __restrict__ xji,
    float* __restrict__ h)
{
    __shared__ float s_Wup[INTD * H];   // 32 KB
    __shared__ float s_acc[4][INTD];
    const int tid = threadIdx.x;
    for (int i = tid; i < INTD * H; i += 256) s_Wup[i] = Wup[i];
    const int w = tid >> 6, lane = tid & 63;
    const int e = blockIdx.x * 4 + w;

    float w2[BE];
    #pragma unroll
    for (int j = 0; j < BE; ++j) w2[j] = W2[j * INTD + lane];

    float acc = 0.0f;
    const int lo = rs[e], hi = rs[e + 1];
    for (int idx = lo; idx < hi; ++idx) {
        const int t  = perm[idx];
        const int kj = idx_kj[t];
        const float* tp = tmp_sb + (size_t)t * BE;
        float sb = 0.0f;
        #pragma unroll
        for (int j = 0; j < BE; ++j) sb = fmaf(tp[j], w2[j], sb);
        acc = fmaf(down[(size_t)kj * INTD + lane], sb, acc);
    }
    s_acc[w][lane] = acc;
    __syncthreads();

    float o0 = 0.0f, o1 = 0.0f;
    #pragma unroll 8
    for (int c = 0; c < INTD; ++c) {
        const float a = s_acc[w][c];
        o0 = fmaf(a, s_Wup[c * H + lane], o0);
        o1 = fmaf(a, s_Wup[c * H + lane + 64], o1);
    }
    const size_t off = (size_t)e * H;
    h[off + lane]      = silu_f(o0) + xji[off + lane];
    h[off + lane + 64] = silu_f(o1) + xji[off + lane + 64];
}

// ---------------------------------------------------------------------------
// Node aggregation (CSR over edge_i): nodes[n,c] = sum_e (rbf[e]@Wrbf[:,c]) * xe[e,c]
// 2 nodes per 256-thread block.
// ---------------------------------------------------------------------------
__global__ __launch_bounds__(256) void k_nodes(
    const int* __restrict__ rs, const int* __restrict__ perm,
    const float* __restrict__ rbf, const float* __restrict__ Wrbf,
    const float* __restrict__ xe, float* __restrict__ nodes)
{
    const int tid = threadIdx.x;
    const int n = blockIdx.x * 2 + (tid >> 7);
    const int c = tid & (H - 1);
    float wr[R];
    #pragma unroll
    for (int i = 0; i < R; ++i) wr[i] = Wrbf[i * H + c];
    float acc = 0.0f;
    const int lo = rs[n], hi = rs[n + 1];
    for (int idx = lo; idx < hi; ++idx) {
        const int e = perm[idx];
        const float* rb = rbf + (size_t)e * R;
        float g = 0.0f;
        #pragma unroll
        for (int i = 0; i < R; ++i) g = fmaf(rb[i], wr[i], g);
        acc = fmaf(g, xe[(size_t)e * H + c], acc);
    }
    nodes[(size_t)n * H + c] = acc;
}

// ---------------------------------------------------------------------------
// P[n] += hN[n,:256] @ Wout[:256]   (one wave per node)
// ---------------------------------------------------------------------------
__global__ __launch_bounds__(256) void k_outdot(
    const float* __restrict__ hN, const float* __restrict__ Wout,
    float* __restrict__ P)
{
    int n = blockIdx.x * 4 + (threadIdx.x >> 6);
    int lane = threadIdx.x & 63;
    float s = 0.0f;
    #pragma unroll
    for (int k = lane; k < OE; k += 64) s = fmaf(hN[(size_t)n * OE + k], Wout[k], s);
    #pragma unroll
    for (int off = 32; off; off >>= 1) s += __shfl_down(s, off);
    if (lane == 0) P[n] += s;
}

// ---------------------------------------------------------------------------
extern "C" void kernel_launch(void* const* d_in, const int* in_sizes, int n_in,
                              void* d_out, int out_size, void* d_ws, size_t ws_size,
                              hipStream_t stream)
{
    (void)in_sizes; (void)n_in; (void)out_size; (void)ws_size;

    const float* x       = (const float*)d_in[0];
    const float* dist    = (const float*)d_in[1];
    const float* freq    = (const float*)d_in[2];
    const float* sbf     = (const float*)d_in[3];
    const int*   idx_kj  = (const int*)d_in[4];
    const int*   idx_ji  = (const int*)d_in[5];
    const int*   edge_i  = (const int*)d_in[6];
    const float* Wi_rbf1 = (const float*)d_in[8];
    const float* Wi_rbf2 = (const float*)d_in[9];
    const float* Wi_sbf1 = (const float*)d_in[10];
    const float* Wi_sbf2 = (const float*)d_in[11];
    const float* Wi_kj   = (const float*)d_in[12];
    const float* bi_kj   = (const float*)d_in[13];
    const float* Wi_ji   = (const float*)d_in[14];
    const float* bi_ji   = (const float*)d_in[15];
    const float* Wi_down = (const float*)d_in[16];
    const float* Wi_up   = (const float*)d_in[17];
    const float* Wi_res  = (const float*)d_in[18];
    const float* bi_res  = (const float*)d_in[19];
    const float* Wi_lin  = (const float*)d_in[20];
    const float* bi_lin  = (const float*)d_in[21];
    const float* Wo_rbf  = (const float*)d_in[22];
    const float* Wo_up   = (const float*)d_in[23];
    const float* bo_up   = (const float*)d_in[24];
    const float* Wo_lin  = (const float*)d_in[25];
    const float* bo_lin  = (const float*)d_in[26];
    const float* Wo_out  = (const float*)d_in[27];
    float* P = (float*)d_out;

    // ---- workspace carve-up (~376 MB) ----
    float* w     = (float*)d_ws;
    float* rbf   = w;  w += (size_t)E * R;
    float* xeA   = w;  w += (size_t)E * H;
    float* xeB   = w;  w += (size_t)E * H;
    float* xji   = w;  w += (size_t)E * H;
    float* xkj   = w;  w += (size_t)E * H;
    float* rbt   = w;  w += (size_t)E * H;     // rb, then residual temp
    float* down  = w;  w += (size_t)E * INTD;
    // union region: out-block buffers | triplet tmp_sb (lifetimes disjoint)
    float* U     = w;  w += (size_t)NN * H + 2 * (size_t)NN * OE;  // 7.68M floats
    float* nodes = U;
    float* hN1   = U + (size_t)NN * H;
    float* hN2   = hN1 + (size_t)NN * OE;
    float* tmp_sb = U;                          // T*BE = 6.4M floats <= 7.68M
    int* ip       = (int*)w;
    int* trip_rs  = ip;  ip += E + 1;
    int* trip_cur = ip;  ip += E;
    int* perm_t   = ip;  ip += T;
    int* edge_rs  = ip;  ip += NN + 1;
    int* edge_cur = ip;  ip += NN;
    int* perm_e   = ip;  ip += E;

    // ---- CSR build (once; reused by both interaction blocks & all out blocks)
    hipMemsetAsync(trip_cur, 0, (size_t)E * sizeof(int), stream);
    hipMemsetAsync(edge_cur, 0, (size_t)NN * sizeof(int), stream);
    k_count<<<(T + 255) / 256, 256, 0, stream>>>(idx_ji, T, trip_cur);
    k_count<<<(E + 255) / 256, 256, 0, stream>>>(edge_i, E, edge_cur);
    k_scan<<<1, 1024, 0, stream>>>(trip_cur, E, trip_rs, trip_cur);
    k_scan<<<1, 1024, 0, stream>>>(edge_cur, NN, edge_rs, edge_cur);
    k_fill<<<(T + 255) / 256, 256, 0, stream>>>(idx_ji, T, trip_cur, perm_t);
    k_fill<<<(E + 255) / 256, 256, 0, stream>>>(edge_i, E, edge_cur, perm_e);

    hipMemsetAsync(d_out, 0, (size_t)NN * sizeof(float), stream);
    k_rbf<<<(E + 255) / 256, 256, 0, stream>>>(dist, freq, rbf);

    auto out_block = [&](int b, const float* xe) {
        k_nodes<<<NN / 2, 256, 0, stream>>>(edge_rs, perm_e, rbf,
                                            Wo_rbf + (size_t)b * R * H, xe, nodes);
        gemm<H, OE, 8, false, true, false, false>(nodes, Wo_up + (size_t)b * H * OE,
                                                  bo_up + (size_t)b * OE,
                                                  nullptr, nullptr, hN1, NN, stream);
        gemm<OE, OE, 8, true, true, false, false>(hN1, Wo_lin + (size_t)(b * 3 + 0) * OE * OE,
                                                  bo_lin + (size_t)(b * 3 + 0) * OE,
                                                  nullptr, nullptr, hN2, NN, stream);
        gemm<OE, OE, 8, true, true, false, false>(hN2, Wo_lin + (size_t)(b * 3 + 1) * OE * OE,
                                                  bo_lin + (size_t)(b * 3 + 1) * OE,
                                                  nullptr, nullptr, hN1, NN, stream);
        gemm<OE, OE, 8, true, true, false, false>(hN1, Wo_lin + (size_t)(b * 3 + 2) * OE * OE,
                                                  bo_lin + (size_t)(b * 3 + 2) * OE,
                                                  nullptr, nullptr, hN2, NN, stream);
        k_outdot<<<NN / 4, 256, 0, stream>>>(hN2, Wo_out + (size_t)b * OE, P);
    };

    auto interact = [&](int b, const float* xe, float* h) {
        gemm<H, H, 8, true, true, false, false>(xe, Wi_ji + (size_t)b * H * H,
                                                bi_ji + (size_t)b * H,
                                                nullptr, nullptr, xji, E, stream);
        gemm<H, H, 8, true, true, false, false>(xe, Wi_kj + (size_t)b * H * H,
                                                bi_kj + (size_t)b * H,
                                                nullptr, nullptr, xkj, E, stream);
        k_rb<<<E * H / 256, 256, 0, stream>>>(rbf, Wi_rbf1 + (size_t)b * R * BE,
                                              Wi_rbf2 + (size_t)b * BE * H, rbt);
        gemm<H, INTD, 4, true, false, true, false>(xkj, Wi_down + (size_t)b * H * INTD,
                                                   nullptr, rbt, nullptr, down, E, stream);
        k_sbfproj<<<T / 32, 256, 0, stream>>>(sbf, Wi_sbf1 + (size_t)b * SR * BE, tmp_sb);
        k_aggup<<<E / 4, 256, 0, stream>>>(trip_rs, perm_t, idx_kj, tmp_sb, down,
                                           Wi_sbf2 + (size_t)b * BE * INTD,
                                           Wi_up + (size_t)b * INTD * H, xji, h);
        // residual 0 (before skip)
        {
            const float* W0 = Wi_res + ((size_t)(b * 3 + 0) * 2 + 0) * H * H;
            const float* b0 = bi_res + ((size_t)(b * 3 + 0) * 2 + 0) * H;
            const float* W1 = Wi_res + ((size_t)(b * 3 + 0) * 2 + 1) * H * H;
            const float* b1 = bi_res + ((size_t)(b * 3 + 0) * 2 + 1) * H;
            gemm<H, H, 8, true, true, false, false>(h, W0, b0, nullptr, nullptr, rbt, E, stream);
            gemm<H, H, 8, true, true, false, true>(rbt, W1, b1, nullptr, h, h, E, stream);
        }
        // skip: h = silu(h@Wi_lin + b) + xe
        gemm<H, H, 8, true, true, false, true>(h, Wi_lin + (size_t)b * H * H,
                                               bi_lin + (size_t)b * H,
                                               nullptr, xe, h, E, stream);
        // residuals 1,2 (after skip)
        for (int r = 1; r <= 2; ++r) {
            const float* W0 = Wi_res + ((size_t)(b * 3 + r) * 2 + 0) * H * H;
            const float* b0 = bi_res + ((size_t)(b * 3 + r) * 2 + 0) * H;
            const float* W1 = Wi_res + ((size_t)(b * 3 + r) * 2 + 1) * H * H;
            const float* b1 = bi_res + ((size_t)(b * 3 + r) * 2 + 1) * H;
            gemm<H, H, 8, true, true, false, false>(h, W0, b0, nullptr, nullptr, rbt, E, stream);
            gemm<H, H, 8, true, true, false, true>(rbt, W1, b1, nullptr, h, h, E, stream);
        }
    };

    out_block(0, x);
    interact(0, x, xeB);
    out_block(1, xeB);
    interact(1, xeB, xeA);
    out_block(2, xeA);
}

// Round 3
// 3148.796 us; speedup vs baseline: 1.6390x; 1.0138x over previous
//
#include <hip/hip_runtime.h>
#include <hip/hip_bf16.h>

// DimeNet++ forward, f32, CSR-gather + L1-tiled GEMM version.
namespace {
constexpr int E     = 120000;   // edges
constexpr int T     = 800000;   // triplets
constexpr int NN    = 12000;    // nodes
constexpr int H     = 128;      // hidden
constexpr int INTD  = 64;       // int_emb
constexpr int BE    = 8;        // basis_emb
constexpr int R     = 6;        // num_radial
constexpr int SR    = 42;       // num_spherical * num_radial
constexpr int OE    = 256;      // out_emb
constexpr float CUTOFF = 5.0f;
}

__device__ __forceinline__ float silu_f(float x) {
    return x / (1.0f + __expf(-x));
}

// ---------------------------------------------------------------------------
// rbf[E,6] = envelope(d) * sin(freq*d), d = dist/cutoff
// ---------------------------------------------------------------------------
__global__ void k_rbf(const float* __restrict__ dist, const float* __restrict__ freq,
                      float* __restrict__ rbf) {
    int e = blockIdx.x * blockDim.x + threadIdx.x;
    if (e >= E) return;
    float d  = dist[e] * (1.0f / CUTOFF);
    float d2 = d * d;
    float d5 = d2 * d2 * d;
    float env = 1.0f / d - 28.0f * d5 + 48.0f * d5 * d - 21.0f * d5 * d2;
    #pragma unroll
    for (int i = 0; i < R; ++i) {
        rbf[e * R + i] = env * sinf(freq[i] * d);
    }
}

// ---------------------------------------------------------------------------
// CSR build: count -> scan -> fill
// ---------------------------------------------------------------------------
__global__ void k_count(const int* __restrict__ idx, int n, int* __restrict__ cnt) {
    int i = blockIdx.x * 256 + threadIdx.x;
    if (i < n) atomicAdd(&cnt[idx[i]], 1);
}

__global__ __launch_bounds__(1024) void k_scan(const int* __restrict__ cnt, int n,
                                               int* __restrict__ rs, int* __restrict__ cur) {
    __shared__ int part[1024];
    const int tid = threadIdx.x;
    const int chunk = (n + 1023) / 1024;
    const int lo = tid * chunk;
    const int hi = min(lo + chunk, n);
    int s = 0;
    for (int i = lo; i < hi; ++i) s += cnt[i];
    part[tid] = s;
    __syncthreads();
    for (int off = 1; off < 1024; off <<= 1) {
        int v = (tid >= off) ? part[tid - off] : 0;
        __syncthreads();
        part[tid] += v;
        __syncthreads();
    }
    int base = (tid == 0) ? 0 : part[tid - 1];
    for (int i = lo; i < hi; ++i) {
        int c = cnt[i];
        rs[i] = base;
        cur[i] = base;
        base += c;
    }
    if (tid == 1023) rs[n] = base;
}

// edge_i CSR fill (perm only)
__global__ void k_fill(const int* __restrict__ idx, int n, int* __restrict__ cur,
                       int* __restrict__ perm) {
    int i = blockIdx.x * 256 + threadIdx.x;
    if (i < n) perm[atomicAdd(&cur[idx[i]], 1)] = i;
}

// triplet CSR fill: also materialize sorted idx_kj and rank[t]=sorted position
__global__ void k_fill_trip(const int* __restrict__ idx_ji, const int* __restrict__ idx_kj,
                            int n, int* __restrict__ cur,
                            int* __restrict__ kjs, int* __restrict__ rank) {
    int i = blockIdx.x * 256 + threadIdx.x;
    if (i < n) {
        int pos = atomicAdd(&cur[idx_ji[i]], 1);
        kjs[pos]  = idx_kj[i];
        rank[i]   = pos;
    }
}

// ---------------------------------------------------------------------------
// Column-tiled GEMM: C[M,NCOL] = act(A[M,K](.*pre) @ W[K,NCOL] + bias) + post
// Block: 256 threads computes ROWS x 64 tile; grid = (ceil(M/ROWS), NCOL/64).
// W column-slice is 64 cols -> <=64KB ... K*64*4B <= 64KB; k-rows re-read hit L1.
// A tile staged in LDS as float4 with +1 float4 row pad (2-way bank = free).
// Aliasing: C==post safe (tile-local), A must differ from C.
// ---------------------------------------------------------------------------
template<int K, int NCOL, int RPT, bool SILU, bool BIAS, bool PRE, bool POST>
__global__ __launch_bounds__(256) void k_gemm2(
    const float* __restrict__ A, const float* __restrict__ W,
    const float* __restrict__ bias, const float* __restrict__ pre,
    const float* __restrict__ post, float* __restrict__ C, int M)
{
    constexpr int CG   = 16;             // 64 cols = 16 float4 groups
    constexpr int RG   = 16;             // 256/CG
    constexpr int ROWS = RG * RPT;
    constexpr int K4   = K / 4;
    constexpr int KP4  = K4 + 1;         // padded row length (float4 units)
    __shared__ float4 As4[ROWS * KP4];

    const int tid = threadIdx.x;
    const int r0  = blockIdx.x * ROWS;
    const int cb  = blockIdx.y * CG;     // col base in float4 units

    // stage A rows (guarded, zero-fill OOB)
    constexpr int TOT4 = ROWS * K4;
    const float4* A4 = reinterpret_cast<const float4*>(A);
    const float4* P4 = reinterpret_cast<const float4*>(pre);
    for (int i = tid; i < TOT4; i += 256) {
        const int row = i / K4, kk = i % K4;
        const int grow = r0 + row;
        float4 v = make_float4(0.f, 0.f, 0.f, 0.f);
        if (grow < M) {
            v = A4[(size_t)grow * K4 + kk];
            if constexpr (PRE) {
                float4 p = P4[(size_t)grow * K4 + kk];
                v.x *= p.x; v.y *= p.y; v.z *= p.z; v.w *= p.w;
            }
        }
        As4[row * KP4 + kk] = v;
    }
    __syncthreads();

    const int cg = tid & 15;
    const int rq = tid >> 4;

    float acc[RPT][4];
    if constexpr (BIAS) {
        const float4 bv = *reinterpret_cast<const float4*>(bias + (cb + cg) * 4);
        #pragma unroll
        for (int r = 0; r < RPT; ++r) {
            acc[r][0] = bv.x; acc[r][1] = bv.y; acc[r][2] = bv.z; acc[r][3] = bv.w;
        }
    } else {
        #pragma unroll
        for (int r = 0; r < RPT; ++r)
            #pragma unroll
            for (int j = 0; j < 4; ++j) acc[r][j] = 0.0f;
    }

    const float4* W4 = reinterpret_cast<const float4*>(W);
    #pragma unroll 4
    for (int k4 = 0; k4 < K4; ++k4) {
        float4 wv[4];
        #pragma unroll
        for (int kk = 0; kk < 4; ++kk)
            wv[kk] = W4[(size_t)(k4 * 4 + kk) * (NCOL / 4) + cb + cg];
        #pragma unroll
        for (int r = 0; r < RPT; ++r) {
            const float4 a = As4[(rq * RPT + r) * KP4 + k4];
            acc[r][0] = fmaf(a.x, wv[0].x, acc[r][0]);
            acc[r][1] = fmaf(a.x, wv[0].y, acc[r][1]);
            acc[r][2] = fmaf(a.x, wv[0].z, acc[r][2]);
            acc[r][3] = fmaf(a.x, wv[0].w, acc[r][3]);
            acc[r][0] = fmaf(a.y, wv[1].x, acc[r][0]);
            acc[r][1] = fmaf(a.y, wv[1].y, acc[r][1]);
            acc[r][2] = fmaf(a.y, wv[1].z, acc[r][2]);
            acc[r][3] = fmaf(a.y, wv[1].w, acc[r][3]);
            acc[r][0] = fmaf(a.z, wv[2].x, acc[r][0]);
            acc[r][1] = fmaf(a.z, wv[2].y, acc[r][1]);
            acc[r][2] = fmaf(a.z, wv[2].z, acc[r][2]);
            acc[r][3] = fmaf(a.z, wv[2].w, acc[r][3]);
            acc[r][0] = fmaf(a.w, wv[3].x, acc[r][0]);
            acc[r][1] = fmaf(a.w, wv[3].y, acc[r][1]);
            acc[r][2] = fmaf(a.w, wv[3].z, acc[r][2]);
            acc[r][3] = fmaf(a.w, wv[3].w, acc[r][3]);
        }
    }

    #pragma unroll
    for (int r = 0; r < RPT; ++r) {
        const int row = r0 + rq * RPT + r;
        if (row >= M) continue;
        float4 v = make_float4(acc[r][0], acc[r][1], acc[r][2], acc[r][3]);
        if constexpr (SILU) {
            v.x = silu_f(v.x); v.y = silu_f(v.y);
            v.z = silu_f(v.z); v.w = silu_f(v.w);
        }
        const size_t off = (size_t)row * NCOL + (cb + cg) * 4;
        if constexpr (POST) {
            const float4 pv = *reinterpret_cast<const float4*>(post + off);
            v.x += pv.x; v.y += pv.y; v.z += pv.z; v.w += pv.w;
        }
        *reinterpret_cast<float4*>(C + off) = v;
    }
}

template<int K, int NCOL, int RPT, bool SILU, bool BIAS, bool PRE, bool POST>
static void gemm2(const float* A, const float* W, const float* bias, const float* pre,
                  const float* post, float* C, int M, hipStream_t s)
{
    constexpr int ROWS = 16 * RPT;
    dim3 g((M + ROWS - 1) / ROWS, NCOL / 64);
    k_gemm2<K, NCOL, RPT, SILU, BIAS, PRE, POST><<<g, 256, 0, s>>>(A, W, bias, pre, post, C, M);
}

// ---------------------------------------------------------------------------
// rb[E,H] = (rbf[E,6] @ W1[6,8]) @ W2[8,128]
// ---------------------------------------------------------------------------
__global__ __launch_bounds__(256) void k_rb(
    const float* __restrict__ rbf, const float* __restrict__ W1,
    const float* __restrict__ W2, float* __restrict__ rb)
{
    int idx = blockIdx.x * 256 + threadIdx.x;   // over E*H
    int e = idx >> 7;
    int c = idx & (H - 1);
    if (e >= E) return;
    float r6[R];
    #pragma unroll
    for (int i = 0; i < R; ++i) r6[i] = rbf[e * R + i];
    float out = 0.0f;
    #pragma unroll
    for (int j = 0; j < BE; ++j) {
        float tj = 0.0f;
        #pragma unroll
        for (int i = 0; i < R; ++i) tj = fmaf(r6[i], W1[i * BE + j], tj);
        out = fmaf(tj, W2[j * H + c], out);
    }
    rb[idx] = out;
}

// ---------------------------------------------------------------------------
// tmp_sorted[rank[t], 8] = sbf[t,42] @ W1[42,8]   (32 triplets / block)
// ---------------------------------------------------------------------------
__global__ __launch_bounds__(256) void k_sbfproj(
    const float* __restrict__ sbf, const float* __restrict__ W1,
    const int* __restrict__ rank, float* __restrict__ tmp)
{
    __shared__ float s_sbf[32 * SR];
    __shared__ float s_W1[SR * BE];
    const int tid = threadIdx.x;
    const int t0  = blockIdx.x * 32;
    for (int i = tid; i < SR * BE; i += 256) s_W1[i] = W1[i];
    const float* sb0 = sbf + (size_t)t0 * SR;
    for (int i = tid; i < 32 * SR; i += 256) s_sbf[i] = sb0[i];
    __syncthreads();
    const int tt = tid >> 3, j = tid & 7;
    float s = 0.0f;
    #pragma unroll
    for (int i = 0; i < SR; ++i) s = fmaf(s_sbf[tt * SR + i], s_W1[i * BE + j], s);
    tmp[(size_t)rank[t0 + tt] * BE + j] = s;
}

// ---------------------------------------------------------------------------
// Edge aggregation over sorted triplets, one wave per edge, no LDS:
//   agg[e,c] = sum_{idx in [rs[e],rs[e+1])} down[kjs[idx],c] * (tmps[idx]@W2[:,c])
// ---------------------------------------------------------------------------
__global__ __launch_bounds__(256) void k_agg(
    const int* __restrict__ rs, const int* __restrict__ kjs,
    const float* __restrict__ tmps, const float* __restrict__ down,
    const float* __restrict__ W2, float* __restrict__ agg)
{
    const int w = threadIdx.x >> 6, lane = threadIdx.x & 63;
    const int e = blockIdx.x * 4 + w;
    float w2[BE];
    #pragma unroll
    for (int j = 0; j < BE; ++j) w2[j] = W2[j * INTD + lane];

    const float4* tmps4 = reinterpret_cast<const float4*>(tmps);
    const int lo = rs[e], hi = rs[e + 1];
    float acc = 0.0f;
    int idx = lo;
    for (; idx + 1 < hi; idx += 2) {
        const int kja = kjs[idx], kjb = kjs[idx + 1];
        const float4 a0 = tmps4[2 * idx],     a1 = tmps4[2 * idx + 1];
        const float4 b0 = tmps4[2 * idx + 2], b1 = tmps4[2 * idx + 3];
        const float da = down[(size_t)kja * INTD + lane];
        const float db = down[(size_t)kjb * INTD + lane];
        float sa = a0.x * w2[0] + a0.y * w2[1] + a0.z * w2[2] + a0.w * w2[3]
                 + a1.x * w2[4] + a1.y * w2[5] + a1.z * w2[6] + a1.w * w2[7];
        float sb = b0.x * w2[0] + b0.y * w2[1] + b0.z * w2[2] + b0.w * w2[3]
                 + b1.x * w2[4] + b1.y * w2[5] + b1.z * w2[6] + b1.w * w2[7];
        acc = fmaf(da, sa, acc);
        acc = fmaf(db, sb, acc);
    }
    if (idx < hi) {
        const int kj = kjs[idx];
        const float4 a0 = tmps4[2 * idx], a1 = tmps4[2 * idx + 1];
        const float d = down[(size_t)kj * INTD + lane];
        float sa = a0.x * w2[0] + a0.y * w2[1] + a0.z * w2[2] + a0.w * w2[3]
                 + a1.x * w2[4] + a1.y * w2[5] + a1.z * w2[6] + a1.w * w2[7];
        acc = fmaf(d, sa, acc);
    }
    agg[(size_t)e * INTD + lane] = acc;
}

// ---------------------------------------------------------------------------
// Node aggregation (CSR over edge_i): nodes[n,c] = sum_e (rbf[e]@Wrbf[:,c]) * xe[e,c]
// ---------------------------------------------------------------------------
__global__ __launch_bounds__(256) void k_nodes(
    const int* __restrict__ rs, const int* __restrict__ perm,
    const float* __restrict__ rbf, const float* __restrict__ Wrbf,
    const float* __restrict__ xe, float* __restrict__ nodes)
{
    const int tid = threadIdx.x;
    const int n = blockIdx.x * 2 + (tid >> 7);
    const int c = tid & (H - 1);
    float wr[R];
    #pragma unroll
    for (int i = 0; i < R; ++i) wr[i] = Wrbf[i * H + c];
    float acc = 0.0f;
    const int lo = rs[n], hi = rs[n + 1];
    for (int idx = lo; idx < hi; ++idx) {
        const int e = perm[idx];
        const float* rb = rbf + (size_t)e * R;
        float g = 0.0f;
        #pragma unroll
        for (int i = 0; i < R; ++i) g = fmaf(rb[i], wr[i], g);
        acc = fmaf(g, xe[(size_t)e * H + c], acc);
    }
    nodes[(size_t)n * H + c] = acc;
}

// ---------------------------------------------------------------------------
// P[n] += hN[n,:256] @ Wout[:256]   (one wave per node)
// ---------------------------------------------------------------------------
__global__ __launch_bounds__(256) void k_outdot(
    const float* __restrict__ hN, const float* __restrict__ Wout,
    float* __restrict__ P)
{
    int n = blockIdx.x * 4 + (threadIdx.x >> 6);
    int lane = threadIdx.x & 63;
    float s = 0.0f;
    #pragma unroll
    for (int k = lane; k < OE; k += 64) s = fmaf(hN[(size_t)n * OE + k], Wout[k], s);
    #pragma unroll
    for (int off = 32; off; off >>= 1) s += __shfl_down(s, off);
    if (lane == 0) P[n] += s;
}

// ---------------------------------------------------------------------------
extern "C" void kernel_launch(void* const* d_in, const int* in_sizes, int n_in,
                              void* d_out, int out_size, void* d_ws, size_t ws_size,
                              hipStream_t stream)
{
    (void)in_sizes; (void)n_in; (void)out_size; (void)ws_size;

    const float* x       = (const float*)d_in[0];
    const float* dist    = (const float*)d_in[1];
    const float* freq    = (const float*)d_in[2];
    const float* sbf     = (const float*)d_in[3];
    const int*   idx_kj  = (const int*)d_in[4];
    const int*   idx_ji  = (const int*)d_in[5];
    const int*   edge_i  = (const int*)d_in[6];
    const float* Wi_rbf1 = (const float*)d_in[8];
    const float* Wi_rbf2 = (const float*)d_in[9];
    const float* Wi_sbf1 = (const float*)d_in[10];
    const float* Wi_sbf2 = (const float*)d_in[11];
    const float* Wi_kj   = (const float*)d_in[12];
    const float* bi_kj   = (const float*)d_in[13];
    const float* Wi_ji   = (const float*)d_in[14];
    const float* bi_ji   = (const float*)d_in[15];
    const float* Wi_down = (const float*)d_in[16];
    const float* Wi_up   = (const float*)d_in[17];
    const float* Wi_res  = (const float*)d_in[18];
    const float* bi_res  = (const float*)d_in[19];
    const float* Wi_lin  = (const float*)d_in[20];
    const float* bi_lin  = (const float*)d_in[21];
    const float* Wo_rbf  = (const float*)d_in[22];
    const float* Wo_up   = (const float*)d_in[23];
    const float* bo_up   = (const float*)d_in[24];
    const float* Wo_lin  = (const float*)d_in[25];
    const float* bo_lin  = (const float*)d_in[26];
    const float* Wo_out  = (const float*)d_in[27];
    float* P = (float*)d_out;

    // ---- workspace carve-up ----
    float* w     = (float*)d_ws;
    float* rbf   = w;  w += (size_t)E * R;
    float* xeA   = w;  w += (size_t)E * H;
    float* xeB   = w;  w += (size_t)E * H;
    float* xji   = w;  w += (size_t)E * H;
    float* xkj   = w;  w += (size_t)E * H;
    float* rbt   = w;  w += (size_t)E * H;     // rb / residual temp
    float* down  = w;  w += (size_t)E * INTD;
    float* agg   = w;  w += (size_t)E * INTD;
    // union region: out-block buffers | triplet tmp_sb (lifetimes disjoint)
    float* U     = w;  w += (size_t)NN * H + 2 * (size_t)NN * OE;  // 7.68M floats
    float* nodes = U;
    float* hN1   = U + (size_t)NN * H;
    float* hN2   = hN1 + (size_t)NN * OE;
    float* tmp_sb = U;                          // T*BE = 6.4M floats <= 7.68M
    int* ip       = (int*)w;
    int* trip_rs  = ip;  ip += E + 1;
    int* trip_cur = ip;  ip += E;
    int* rank_t   = ip;  ip += T;
    int* kjs      = ip;  ip += T;
    int* edge_rs  = ip;  ip += NN + 1;
    int* edge_cur = ip;  ip += NN;
    int* perm_e   = ip;  ip += E;

    // ---- CSR build (reused across all blocks) ----
    hipMemsetAsync(trip_cur, 0, (size_t)E * sizeof(int), stream);
    hipMemsetAsync(edge_cur, 0, (size_t)NN * sizeof(int), stream);
    k_count<<<(T + 255) / 256, 256, 0, stream>>>(idx_ji, T, trip_cur);
    k_count<<<(E + 255) / 256, 256, 0, stream>>>(edge_i, E, edge_cur);
    k_scan<<<1, 1024, 0, stream>>>(trip_cur, E, trip_rs, trip_cur);
    k_scan<<<1, 1024, 0, stream>>>(edge_cur, NN, edge_rs, edge_cur);
    k_fill_trip<<<(T + 255) / 256, 256, 0, stream>>>(idx_ji, idx_kj, T, trip_cur, kjs, rank_t);
    k_fill<<<(E + 255) / 256, 256, 0, stream>>>(edge_i, E, edge_cur, perm_e);

    hipMemsetAsync(d_out, 0, (size_t)NN * sizeof(float), stream);
    k_rbf<<<(E + 255) / 256, 256, 0, stream>>>(dist, freq, rbf);

    auto out_block = [&](int b, const float* xe) {
        k_nodes<<<NN / 2, 256, 0, stream>>>(edge_rs, perm_e, rbf,
                                            Wo_rbf + (size_t)b * R * H, xe, nodes);
        gemm2<H, OE, 4, false, true, false, false>(nodes, Wo_up + (size_t)b * H * OE,
                                                   bo_up + (size_t)b * OE,
                                                   nullptr, nullptr, hN1, NN, stream);
        gemm2<OE, OE, 2, true, true, false, false>(hN1, Wo_lin + (size_t)(b * 3 + 0) * OE * OE,
                                                   bo_lin + (size_t)(b * 3 + 0) * OE,
                                                   nullptr, nullptr, hN2, NN, stream);
        gemm2<OE, OE, 2, true, true, false, false>(hN2, Wo_lin + (size_t)(b * 3 + 1) * OE * OE,
                                                   bo_lin + (size_t)(b * 3 + 1) * OE,
                                                   nullptr, nullptr, hN1, NN, stream);
        gemm2<OE, OE, 2, true, true, false, false>(hN1, Wo_lin + (size_t)(b * 3 + 2) * OE * OE,
                                                   bo_lin + (size_t)(b * 3 + 2) * OE,
                                                   nullptr, nullptr, hN2, NN, stream);
        k_outdot<<<NN / 4, 256, 0, stream>>>(hN2, Wo_out + (size_t)b * OE, P);
    };

    auto interact = [&](int b, const float* xe, float* out) {
        // 1-2: edge projections
        gemm2<H, H, 4, true, true, false, false>(xe, Wi_ji + (size_t)b * H * H,
                                                 bi_ji + (size_t)b * H,
                                                 nullptr, nullptr, xji, E, stream);
        gemm2<H, H, 4, true, true, false, false>(xe, Wi_kj + (size_t)b * H * H,
                                                 bi_kj + (size_t)b * H,
                                                 nullptr, nullptr, xkj, E, stream);
        // 3: rb
        k_rb<<<E * H / 256, 256, 0, stream>>>(rbf, Wi_rbf1 + (size_t)b * R * BE,
                                              Wi_rbf2 + (size_t)b * BE * H, rbt);
        // 4: down = silu((xkj .* rb) @ Wdown)
        gemm2<H, INTD, 4, true, false, true, false>(xkj, Wi_down + (size_t)b * H * INTD,
                                                    nullptr, rbt, nullptr, down, E, stream);
        // 5: triplet basis + aggregation
        k_sbfproj<<<T / 32, 256, 0, stream>>>(sbf, Wi_sbf1 + (size_t)b * SR * BE, rank_t, tmp_sb);
        k_agg<<<E / 4, 256, 0, stream>>>(trip_rs, kjs, tmp_sb, down,
                                         Wi_sbf2 + (size_t)b * BE * INTD, agg);
        // 6: h(xji) = silu(agg @ Wup) + xji      [C==post, safe]
        gemm2<INTD, H, 4, true, false, false, true>(agg, Wi_up + (size_t)b * INTD * H,
                                                    nullptr, nullptr, xji, xji, E, stream);
        const float* Wr = Wi_res + (size_t)(b * 3) * 2 * H * H;
        const float* br = bi_res + (size_t)(b * 3) * 2 * H;
        // 7-8: residual 0 (before skip):  h(rbt) = xji + silu(silu(xji@W00)@W01)
        gemm2<H, H, 4, true, true, false, false>(xji, Wr + 0 * H * H, br + 0 * H,
                                                 nullptr, nullptr, xkj, E, stream);
        gemm2<H, H, 4, true, true, false, true>(xkj, Wr + 1 * H * H, br + 1 * H,
                                                nullptr, xji, rbt, E, stream);
        // 9: skip: h(xji) = silu(rbt@Wlin + b) + xe
        gemm2<H, H, 4, true, true, false, true>(rbt, Wi_lin + (size_t)b * H * H,
                                                bi_lin + (size_t)b * H,
                                                nullptr, xe, xji, E, stream);
        // 10: residual 1: h(rbt) = xji + silu(silu(xji@W10)@W11)
        gemm2<H, H, 4, true, true, false, false>(xji, Wr + 2 * H * H, br + 2 * H,
                                                 nullptr, nullptr, xkj, E, stream);
        gemm2<H, H, 4, true, true, false, true>(xkj, Wr + 3 * H * H, br + 3 * H,
                                                nullptr, xji, rbt, E, stream);
        // 11: residual 2: out = rbt + silu(silu(rbt@W20)@W21)
        gemm2<H, H, 4, true, true, false, false>(rbt, Wr + 4 * H * H, br + 4 * H,
                                                 nullptr, nullptr, xkj, E, stream);
        gemm2<H, H, 4, true, true, false, true>(xkj, Wr + 5 * H * H, br + 5 * H,
                                                nullptr, rbt, out, E, stream);
    };

    out_block(0, x);
    interact(0, x, xeB);
    out_block(1, xeB);
    interact(1, xeB, xeA);
    out_block(2, xeA);
}

// Round 4
// 2430.191 us; speedup vs baseline: 2.1237x; 1.2957x over previous
//
#include <hip/hip_runtime.h>
#include <hip/hip_bf16.h>

// DimeNet++ forward, f32, fully fused row-local chains + CSR gather.
namespace {
constexpr int E     = 120000;
constexpr int T     = 800000;
constexpr int NN    = 12000;
constexpr int H     = 128;
constexpr int INTD  = 64;
constexpr int BE    = 8;
constexpr int R     = 6;
constexpr int SR    = 42;
constexpr int OE    = 256;
constexpr float CUTOFF = 5.0f;
}

__device__ __forceinline__ float silu_f(float x) { return x / (1.0f + __expf(-x)); }
__device__ __forceinline__ float4 silu4(float4 v) {
    return make_float4(silu_f(v.x), silu_f(v.y), silu_f(v.z), silu_f(v.w));
}
__device__ __forceinline__ float4 add4(float4 a, float4 b) {
    return make_float4(a.x + b.x, a.y + b.y, a.z + b.z, a.w + b.w);
}

// acc[4][4] += A(4 rows from rbase, LDS, float4 row stride AS4) @ W[K][WS4*4] col-group cg
template<int K4, int AS4, int WS4>
__device__ __forceinline__ void mmA(const float4* __restrict__ A4, const float4* __restrict__ W4,
                                    int cg, int rbase, float acc[4][4])
{
    #pragma unroll 4
    for (int k4 = 0; k4 < K4; ++k4) {
        const float4 wv0 = W4[(k4 * 4 + 0) * WS4 + cg];
        const float4 wv1 = W4[(k4 * 4 + 1) * WS4 + cg];
        const float4 wv2 = W4[(k4 * 4 + 2) * WS4 + cg];
        const float4 wv3 = W4[(k4 * 4 + 3) * WS4 + cg];
        #pragma unroll
        for (int r = 0; r < 4; ++r) {
            const float4 a = A4[(rbase + r) * AS4 + k4];
            acc[r][0] = fmaf(a.x, wv0.x, acc[r][0]); acc[r][1] = fmaf(a.x, wv0.y, acc[r][1]);
            acc[r][2] = fmaf(a.x, wv0.z, acc[r][2]); acc[r][3] = fmaf(a.x, wv0.w, acc[r][3]);
            acc[r][0] = fmaf(a.y, wv1.x, acc[r][0]); acc[r][1] = fmaf(a.y, wv1.y, acc[r][1]);
            acc[r][2] = fmaf(a.y, wv1.z, acc[r][2]); acc[r][3] = fmaf(a.y, wv1.w, acc[r][3]);
            acc[r][0] = fmaf(a.z, wv2.x, acc[r][0]); acc[r][1] = fmaf(a.z, wv2.y, acc[r][1]);
            acc[r][2] = fmaf(a.z, wv2.z, acc[r][2]); acc[r][3] = fmaf(a.z, wv2.w, acc[r][3]);
            acc[r][0] = fmaf(a.w, wv3.x, acc[r][0]); acc[r][1] = fmaf(a.w, wv3.y, acc[r][1]);
            acc[r][2] = fmaf(a.w, wv3.z, acc[r][2]); acc[r][3] = fmaf(a.w, wv3.w, acc[r][3]);
        }
    }
}

__device__ __forceinline__ void acc_zero(float acc[4][4]) {
    #pragma unroll
    for (int r = 0; r < 4; ++r)
        #pragma unroll
        for (int j = 0; j < 4; ++j) acc[r][j] = 0.0f;
}
__device__ __forceinline__ void acc_bias(float acc[4][4], const float* bias, int cg) {
    const float4 bv = reinterpret_cast<const float4*>(bias)[cg];
    #pragma unroll
    for (int r = 0; r < 4; ++r) {
        acc[r][0] = bv.x; acc[r][1] = bv.y; acc[r][2] = bv.z; acc[r][3] = bv.w;
    }
}
__device__ __forceinline__ float4 acc4(const float acc[4][4], int r) {
    return make_float4(acc[r][0], acc[r][1], acc[r][2], acc[r][3]);
}

// ---------------------------------------------------------------------------
// rbf[E,6]
// ---------------------------------------------------------------------------
__global__ void k_rbf(const float* __restrict__ dist, const float* __restrict__ freq,
                      float* __restrict__ rbf) {
    int e = blockIdx.x * blockDim.x + threadIdx.x;
    if (e >= E) return;
    float d  = dist[e] * (1.0f / CUTOFF);
    float d2 = d * d;
    float d5 = d2 * d2 * d;
    float env = 1.0f / d - 28.0f * d5 + 48.0f * d5 * d - 21.0f * d5 * d2;
    #pragma unroll
    for (int i = 0; i < R; ++i) rbf[e * R + i] = env * sinf(freq[i] * d);
}

// ---------------------------------------------------------------------------
// CSR build: count -> (blockred, tiny scan, fill_rs) -> fill
// ---------------------------------------------------------------------------
__global__ void k_count(const int* __restrict__ idx, int n, int* __restrict__ cnt) {
    int i = blockIdx.x * 256 + threadIdx.x;
    if (i < n) atomicAdd(&cnt[idx[i]], 1);
}

__global__ __launch_bounds__(256) void k_red(const int* __restrict__ cnt, int n,
                                             int* __restrict__ bsum) {
    __shared__ int ws[4];
    const int tid = threadIdx.x;
    const int base = blockIdx.x * 2048 + tid * 8;
    int s = 0;
    #pragma unroll
    for (int k = 0; k < 8; ++k) { int i = base + k; s += (i < n) ? cnt[i] : 0; }
    #pragma unroll
    for (int off = 32; off; off >>= 1) s += __shfl_down(s, off);
    if ((tid & 63) == 0) ws[tid >> 6] = s;
    __syncthreads();
    if (tid == 0) bsum[blockIdx.x] = ws[0] + ws[1] + ws[2] + ws[3];
}

__global__ void k_scanb(int* __restrict__ b, int nb) {   // nb <= 64; 64 threads
    __shared__ int s[64];
    const int tid = threadIdx.x;
    if (tid < nb) s[tid] = b[tid];
    __syncthreads();
    if (tid == 0) {
        int run = 0;
        for (int i = 0; i < nb; ++i) { int c = s[i]; s[i] = run; run += c; }
    }
    __syncthreads();
    if (tid < nb) b[tid] = s[tid];
}

__global__ __launch_bounds__(256) void k_fill_rs(const int* __restrict__ cnt, int n,
                                                 const int* __restrict__ boff,
                                                 int* __restrict__ rs, int* __restrict__ cur) {
    __shared__ int ts[256];
    const int tid = threadIdx.x;
    const int base = blockIdx.x * 2048 + tid * 8;
    int v[8]; int s = 0;
    #pragma unroll
    for (int k = 0; k < 8; ++k) { int i = base + k; v[k] = (i < n) ? cnt[i] : 0; s += v[k]; }
    ts[tid] = s;
    __syncthreads();
    for (int off = 1; off < 256; off <<= 1) {
        int t = (tid >= off) ? ts[tid - off] : 0;
        __syncthreads();
        ts[tid] += t;
        __syncthreads();
    }
    int ex = boff[blockIdx.x] + ((tid == 0) ? 0 : ts[tid - 1]);
    #pragma unroll
    for (int k = 0; k < 8; ++k) {
        int i = base + k;
        if (i < n) {
            rs[i] = ex; cur[i] = ex; ex += v[k];
            if (i == n - 1) rs[n] = ex;
        }
    }
}

__global__ void k_fill(const int* __restrict__ idx, int n, int* __restrict__ cur,
                       int* __restrict__ perm) {
    int i = blockIdx.x * 256 + threadIdx.x;
    if (i < n) perm[atomicAdd(&cur[idx[i]], 1)] = i;
}

__global__ void k_fill_trip(const int* __restrict__ idx_ji, const int* __restrict__ idx_kj,
                            int n, int* __restrict__ cur,
                            int* __restrict__ kjs, int* __restrict__ rank) {
    int i = blockIdx.x * 256 + threadIdx.x;
    if (i < n) {
        int pos = atomicAdd(&cur[idx_ji[i]], 1);
        kjs[pos] = idx_kj[i];
        rank[i]  = pos;
    }
}

// ---------------------------------------------------------------------------
// Both blocks' sbf projections in ONE pass over sbf (134 MB read once)
// tmp{a,b}[rank[t], 8] = sbf[t,:] @ W1{a,b}
// ---------------------------------------------------------------------------
__global__ __launch_bounds__(256) void k_sbfproj2(
    const float* __restrict__ sbf, const float* __restrict__ W1a,
    const float* __restrict__ W1b, const int* __restrict__ rank,
    float* __restrict__ ta, float* __restrict__ tb)
{
    __shared__ float s_sbf[32 * SR];
    __shared__ float s_Wa[SR * BE];
    __shared__ float s_Wb[SR * BE];
    const int tid = threadIdx.x;
    const int t0  = blockIdx.x * 32;
    for (int i = tid; i < SR * BE; i += 256) { s_Wa[i] = W1a[i]; s_Wb[i] = W1b[i]; }
    const float* sb0 = sbf + (size_t)t0 * SR;
    for (int i = tid; i < 32 * SR; i += 256) s_sbf[i] = sb0[i];
    __syncthreads();
    const int tt = tid >> 3, j = tid & 7;
    float sa = 0.0f, sb = 0.0f;
    #pragma unroll
    for (int i = 0; i < SR; ++i) {
        const float v = s_sbf[tt * SR + i];
        sa = fmaf(v, s_Wa[i * BE + j], sa);
        sb = fmaf(v, s_Wb[i * BE + j], sb);
    }
    const size_t p = (size_t)rank[t0 + tt] * BE + j;
    ta[p] = sa;
    tb[p] = sb;
}

// ---------------------------------------------------------------------------
// Fused front: xji = silu(xe@Wji+b), xkj = silu(xe@Wkj+b) [LDS],
//              rb inline from rbf, down = silu((xkj.*rb)@Wdown)
// 32 rows / 256-thread block.
// ---------------------------------------------------------------------------
__global__ __launch_bounds__(256) void k_front(
    const float* __restrict__ xe, const float* __restrict__ rbf,
    const float* __restrict__ Wji, const float* __restrict__ bji,
    const float* __restrict__ Wkj, const float* __restrict__ bkj,
    const float* __restrict__ W1, const float* __restrict__ W2,
    const float* __restrict__ Wdown,
    float* __restrict__ xji, float* __restrict__ down)
{
    __shared__ float xb[32 * 132];   // xe tile; later rb tile
    __shared__ float kb[32 * 132];   // xkj tile
    __shared__ float s_tj[32 * 8];
    const int tid = threadIdx.x;
    const int r0  = blockIdx.x * 32;
    float4* xb4 = reinterpret_cast<float4*>(xb);
    float4* kb4 = reinterpret_cast<float4*>(kb);
    const float4* XG = reinterpret_cast<const float4*>(xe);

    for (int i = tid; i < 32 * 32; i += 256) {
        int row = i >> 5, kk = i & 31;
        xb4[row * 33 + kk] = XG[(size_t)(r0 + row) * 32 + kk];
    }
    {   // tj[32][8] = rbf_tile @ W1
        const int row = tid >> 3, j = tid & 7;
        const float* rr = rbf + (size_t)(r0 + row) * R;
        float s = 0.0f;
        #pragma unroll
        for (int i = 0; i < R; ++i) s = fmaf(rr[i], W1[i * BE + j], s);
        s_tj[row * 8 + j] = s;
    }
    __syncthreads();

    const int cg = tid & 31, rq = tid >> 5, rbase = rq * 4;
    float acc[4][4];

    // x_ji -> global
    acc_bias(acc, bji, cg);
    mmA<32, 33, 32>(xb4, reinterpret_cast<const float4*>(Wji), cg, rbase, acc);
    #pragma unroll
    for (int r = 0; r < 4; ++r)
        reinterpret_cast<float4*>(xji)[(size_t)(r0 + rbase + r) * 32 + cg] = silu4(acc4(acc, r));

    // x_kj -> kb
    acc_bias(acc, bkj, cg);
    mmA<32, 33, 32>(xb4, reinterpret_cast<const float4*>(Wkj), cg, rbase, acc);
    #pragma unroll
    for (int r = 0; r < 4; ++r) kb4[(rbase + r) * 33 + cg] = silu4(acc4(acc, r));
    __syncthreads();

    // rb -> xb (overwrite; nobody reads xb in this phase)
    {
        const float4* W24 = reinterpret_cast<const float4*>(W2);
        #pragma unroll
        for (int r = 0; r < 4; ++r) {
            const int row = rbase + r;
            float4 a = make_float4(0.f, 0.f, 0.f, 0.f);
            #pragma unroll
            for (int j = 0; j < BE; ++j) {
                const float t = s_tj[row * 8 + j];
                const float4 wv = W24[j * 32 + cg];
                a.x = fmaf(t, wv.x, a.x); a.y = fmaf(t, wv.y, a.y);
                a.z = fmaf(t, wv.z, a.z); a.w = fmaf(t, wv.w, a.w);
            }
            xb4[row * 33 + cg] = a;
        }
    }
    __syncthreads();

    // down = silu((kb .* xb) @ Wdown): 32x64 tile, 2 rows x 4 cols / thread
    {
        const int cg16 = tid & 15, rq16 = tid >> 4;
        const float4* W4 = reinterpret_cast<const float4*>(Wdown);
        float a2[2][4];
        #pragma unroll
        for (int r = 0; r < 2; ++r)
            #pragma unroll
            for (int j = 0; j < 4; ++j) a2[r][j] = 0.0f;
        #pragma unroll 4
        for (int k4 = 0; k4 < 32; ++k4) {
            const float4 wv0 = W4[(k4 * 4 + 0) * 16 + cg16];
            const float4 wv1 = W4[(k4 * 4 + 1) * 16 + cg16];
            const float4 wv2 = W4[(k4 * 4 + 2) * 16 + cg16];
            const float4 wv3 = W4[(k4 * 4 + 3) * 16 + cg16];
            #pragma unroll
            for (int r = 0; r < 2; ++r) {
                const int row = rq16 * 2 + r;
                const float4 xa = kb4[row * 33 + k4];
                const float4 ra = xb4[row * 33 + k4];
                const float ax = xa.x * ra.x, ay = xa.y * ra.y, az = xa.z * ra.z, aw = xa.w * ra.w;
                a2[r][0] = fmaf(ax, wv0.x, a2[r][0]); a2[r][1] = fmaf(ax, wv0.y, a2[r][1]);
                a2[r][2] = fmaf(ax, wv0.z, a2[r][2]); a2[r][3] = fmaf(ax, wv0.w, a2[r][3]);
                a2[r][0] = fmaf(ay, wv1.x, a2[r][0]); a2[r][1] = fmaf(ay, wv1.y, a2[r][1]);
                a2[r][2] = fmaf(ay, wv1.z, a2[r][2]); a2[r][3] = fmaf(ay, wv1.w, a2[r][3]);
                a2[r][0] = fmaf(az, wv2.x, a2[r][0]); a2[r][1] = fmaf(az, wv2.y, a2[r][1]);
                a2[r][2] = fmaf(az, wv2.z, a2[r][2]); a2[r][3] = fmaf(az, wv2.w, a2[r][3]);
                a2[r][0] = fmaf(aw, wv3.x, a2[r][0]); a2[r][1] = fmaf(aw, wv3.y, a2[r][1]);
                a2[r][2] = fmaf(aw, wv3.z, a2[r][2]); a2[r][3] = fmaf(aw, wv3.w, a2[r][3]);
            }
        }
        #pragma unroll
        for (int r = 0; r < 2; ++r) {
            const int row = r0 + rq16 * 2 + r;
            reinterpret_cast<float4*>(down)[(size_t)row * 16 + cg16] =
                silu4(make_float4(a2[r][0], a2[r][1], a2[r][2], a2[r][3]));
        }
    }
}

// ---------------------------------------------------------------------------
// Edge aggregation over sorted triplets (one wave per edge)
// ---------------------------------------------------------------------------
__global__ __launch_bounds__(256) void k_agg(
    const int* __restrict__ rs, const int* __restrict__ kjs,
    const float* __restrict__ tmps, const float* __restrict__ down,
    const float* __restrict__ W2, float* __restrict__ agg)
{
    const int w = threadIdx.x >> 6, lane = threadIdx.x & 63;
    const int e = blockIdx.x * 4 + w;
    float w2[BE];
    #pragma unroll
    for (int j = 0; j < BE; ++j) w2[j] = W2[j * INTD + lane];

    const float4* tmps4 = reinterpret_cast<const float4*>(tmps);
    const int lo = rs[e], hi = rs[e + 1];
    float acc = 0.0f;
    int idx = lo;
    for (; idx + 1 < hi; idx += 2) {
        const int kja = kjs[idx], kjb = kjs[idx + 1];
        const float4 a0 = tmps4[2 * idx],     a1 = tmps4[2 * idx + 1];
        const float4 b0 = tmps4[2 * idx + 2], b1 = tmps4[2 * idx + 3];
        const float da = down[(size_t)kja * INTD + lane];
        const float db = down[(size_t)kjb * INTD + lane];
        float sa = a0.x * w2[0] + a0.y * w2[1] + a0.z * w2[2] + a0.w * w2[3]
                 + a1.x * w2[4] + a1.y * w2[5] + a1.z * w2[6] + a1.w * w2[7];
        float sb = b0.x * w2[0] + b0.y * w2[1] + b0.z * w2[2] + b0.w * w2[3]
                 + b1.x * w2[4] + b1.y * w2[5] + b1.z * w2[6] + b1.w * w2[7];
        acc = fmaf(da, sa, acc);
        acc = fmaf(db, sb, acc);
    }
    if (idx < hi) {
        const int kj = kjs[idx];
        const float4 a0 = tmps4[2 * idx], a1 = tmps4[2 * idx + 1];
        const float d = down[(size_t)kj * INTD + lane];
        float sa = a0.x * w2[0] + a0.y * w2[1] + a0.z * w2[2] + a0.w * w2[3]
                 + a1.x * w2[4] + a1.y * w2[5] + a1.z * w2[6] + a1.w * w2[7];
        acc = fmaf(d, sa, acc);
    }
    agg[(size_t)e * INTD + lane] = acc;
}

// ---------------------------------------------------------------------------
// Fused tail: h0 = silu(agg@Wup)+xji; res0; skip(+xe); res1; res2 -> out
// 32 rows / block, ping-pong LDS tiles, 8 phases.
// ---------------------------------------------------------------------------
__global__ __launch_bounds__(256) void k_tail(
    const float* __restrict__ agg, const float* __restrict__ xji,
    const float* __restrict__ xe,
    const float* __restrict__ Wup,
    const float* __restrict__ Wr, const float* __restrict__ br,
    const float* __restrict__ Wlin, const float* __restrict__ blin,
    float* __restrict__ out)
{
    __shared__ float hb[32 * 132];
    __shared__ float tbuf[32 * 132];
    __shared__ float ab[32 * 68];
    const int tid = threadIdx.x;
    const int r0  = blockIdx.x * 32;
    float4* hb4 = reinterpret_cast<float4*>(hb);
    float4* tb4 = reinterpret_cast<float4*>(tbuf);
    float4* ab4 = reinterpret_cast<float4*>(ab);
    const float4* AG = reinterpret_cast<const float4*>(agg);
    const float4* XJ = reinterpret_cast<const float4*>(xji);
    const float4* XE = reinterpret_cast<const float4*>(xe);

    for (int i = tid; i < 32 * 16; i += 256) {
        int row = i >> 4, kk = i & 15;
        ab4[row * 17 + kk] = AG[(size_t)(r0 + row) * 16 + kk];
    }
    __syncthreads();

    const int cg = tid & 31, rq = tid >> 5, rbase = rq * 4;
    float acc[4][4];

    // p0: h = silu(agg@Wup) + xji
    acc_zero(acc);
    mmA<16, 17, 32>(ab4, reinterpret_cast<const float4*>(Wup), cg, rbase, acc);
    #pragma unroll
    for (int r = 0; r < 4; ++r)
        hb4[(rbase + r) * 33 + cg] = add4(silu4(acc4(acc, r)),
                                          XJ[(size_t)(r0 + rbase + r) * 32 + cg]);
    __syncthreads();

    // p1: t = silu(h@W0+b0)
    acc_bias(acc, br + 0 * H, cg);
    mmA<32, 33, 32>(hb4, reinterpret_cast<const float4*>(Wr + 0 * H * H), cg, rbase, acc);
    #pragma unroll
    for (int r = 0; r < 4; ++r) tb4[(rbase + r) * 33 + cg] = silu4(acc4(acc, r));
    __syncthreads();

    // p2: h += silu(t@W1+b1)
    acc_bias(acc, br + 1 * H, cg);
    mmA<32, 33, 32>(tb4, reinterpret_cast<const float4*>(Wr + 1 * H * H), cg, rbase, acc);
    #pragma unroll
    for (int r = 0; r < 4; ++r) {
        const int i = (rbase + r) * 33 + cg;
        hb4[i] = add4(hb4[i], silu4(acc4(acc, r)));
    }
    __syncthreads();

    // p3: t = silu(h@Wlin+blin) + xe
    acc_bias(acc, blin, cg);
    mmA<32, 33, 32>(hb4, reinterpret_cast<const float4*>(Wlin), cg, rbase, acc);
    #pragma unroll
    for (int r = 0; r < 4; ++r)
        tb4[(rbase + r) * 33 + cg] = add4(silu4(acc4(acc, r)),
                                          XE[(size_t)(r0 + rbase + r) * 32 + cg]);
    __syncthreads();

    // p4: h = silu(t@W2+b2)
    acc_bias(acc, br + 2 * H, cg);
    mmA<32, 33, 32>(tb4, reinterpret_cast<const float4*>(Wr + 2 * H * H), cg, rbase, acc);
    #pragma unroll
    for (int r = 0; r < 4; ++r) hb4[(rbase + r) * 33 + cg] = silu4(acc4(acc, r));
    __syncthreads();

    // p5: t += silu(h@W3+b3)
    acc_bias(acc, br + 3 * H, cg);
    mmA<32, 33, 32>(hb4, reinterpret_cast<const float4*>(Wr + 3 * H * H), cg, rbase, acc);
    #pragma unroll
    for (int r = 0; r < 4; ++r) {
        const int i = (rbase + r) * 33 + cg;
        tb4[i] = add4(tb4[i], silu4(acc4(acc, r)));
    }
    __syncthreads();

    // p6: h = silu(t@W4+b4)
    acc_bias(acc, br + 4 * H, cg);
    mmA<32, 33, 32>(tb4, reinterpret_cast<const float4*>(Wr + 4 * H * H), cg, rbase, acc);
    #pragma unroll
    for (int r = 0; r < 4; ++r) hb4[(rbase + r) * 33 + cg] = silu4(acc4(acc, r));
    __syncthreads();

    // p7: out = t + silu(h@W5+b5)
    acc_bias(acc, br + 5 * H, cg);
    mmA<32, 33, 32>(hb4, reinterpret_cast<const float4*>(Wr + 5 * H * H), cg, rbase, acc);
    #pragma unroll
    for (int r = 0; r < 4; ++r) {
        const int i = (rbase + r) * 33 + cg;
        reinterpret_cast<float4*>(out)[(size_t)(r0 + rbase + r) * 32 + cg] =
            add4(tb4[i], silu4(acc4(acc, r)));
    }
}

// ---------------------------------------------------------------------------
// Node aggregation (CSR over edge_i)
// ---------------------------------------------------------------------------
__global__ __launch_bounds__(256) void k_nodes(
    const int* __restrict__ rs, const int* __restrict__ perm,
    const float* __restrict__ rbf, const float* __restrict__ Wrbf,
    const float* __restrict__ xe, float* __restrict__ nodes)
{
    const int tid = threadIdx.x;
    const int n = blockIdx.x * 2 + (tid >> 7);
    const int c = tid & (H - 1);
    float wr[R];
    #pragma unroll
    for (int i = 0; i < R; ++i) wr[i] = Wrbf[i * H + c];
    float acc = 0.0f;
    const int lo = rs[n], hi = rs[n + 1];
    for (int idx = lo; idx < hi; ++idx) {
        const int e = perm[idx];
        const float* rb = rbf + (size_t)e * R;
        float g = 0.0f;
        #pragma unroll
        for (int i = 0; i < R; ++i) g = fmaf(rb[i], wr[i], g);
        acc = fmaf(g, xe[(size_t)e * H + c], acc);
    }
    nodes[(size_t)n * H + c] = acc;
}

// ---------------------------------------------------------------------------
// Fused output chain: h=nodes@Wup+b; 3x silu(h@Wl+b); P += h@Wout
// 16 rows / 256-thread block; CG=64.
// ---------------------------------------------------------------------------
__global__ __launch_bounds__(256) void k_outchain(
    const float* __restrict__ nodes, const float* __restrict__ Wup,
    const float* __restrict__ bup, const float* __restrict__ Wlin,
    const float* __restrict__ blin, const float* __restrict__ Wout,
    float* __restrict__ P)
{
    __shared__ float nb[16 * 132];
    __shared__ float hb[16 * 260];
    __shared__ float tbuf[16 * 260];
    __shared__ float red[64 * 16];
    const int tid = threadIdx.x;
    const int n0  = blockIdx.x * 16;
    float4* nb4 = reinterpret_cast<float4*>(nb);
    float4* hb4 = reinterpret_cast<float4*>(hb);
    float4* tb4 = reinterpret_cast<float4*>(tbuf);
    const float4* NG = reinterpret_cast<const float4*>(nodes);

    for (int i = tid; i < 16 * 32; i += 256) {
        int row = i >> 5, kk = i & 31;
        nb4[row * 33 + kk] = NG[(size_t)(n0 + row) * 32 + kk];
    }
    __syncthreads();

    const int cg = tid & 63, rq = tid >> 6, rbase = rq * 4;
    float acc[4][4];

    // p0: h = nodes@Wup + bup  (no act)
    acc_bias(acc, bup, cg);
    mmA<32, 33, 64>(nb4, reinterpret_cast<const float4*>(Wup), cg, rbase, acc);
    #pragma unroll
    for (int r = 0; r < 4; ++r) hb4[(rbase + r) * 65 + cg] = acc4(acc, r);
    __syncthreads();

    // p1: t = silu(h@Wl0+b0)
    acc_bias(acc, blin + 0 * OE, cg);
    mmA<64, 65, 64>(hb4, reinterpret_cast<const float4*>(Wlin + 0 * OE * OE), cg, rbase, acc);
    #pragma unroll
    for (int r = 0; r < 4; ++r) tb4[(rbase + r) * 65 + cg] = silu4(acc4(acc, r));
    __syncthreads();

    // p2: h = silu(t@Wl1+b1)
    acc_bias(acc, blin + 1 * OE, cg);
    mmA<64, 65, 64>(tb4, reinterpret_cast<const float4*>(Wlin + 1 * OE * OE), cg, rbase, acc);
    #pragma unroll
    for (int r = 0; r < 4; ++r) hb4[(rbase + r) * 65 + cg] = silu4(acc4(acc, r));
    __syncthreads();

    // p3: t = silu(h@Wl2+b2)
    acc_bias(acc, blin + 2 * OE, cg);
    mmA<64, 65, 64>(hb4, reinterpret_cast<const float4*>(Wlin + 2 * OE * OE), cg, rbase, acc);
    #pragma unroll
    for (int r = 0; r < 4; ++r) tb4[(rbase + r) * 65 + cg] = silu4(acc4(acc, r));
    __syncthreads();

    // p4: P[row] += t[row,:] . Wout
    {
        const float4 wo = reinterpret_cast<const float4*>(Wout)[cg];
        #pragma unroll
        for (int r = 0; r < 4; ++r) {
            const int row = rbase + r;
            const float4 hv = tb4[row * 65 + cg];
            red[cg * 16 + row] = hv.x * wo.x + hv.y * wo.y + hv.z * wo.z + hv.w * wo.w;
        }
    }
    __syncthreads();
    if (tid < 16) {
        float s = 0.0f;
        for (int c = 0; c < 64; ++c) s += red[c * 16 + tid];
        P[n0 + tid] += s;
    }
}

// ---------------------------------------------------------------------------
extern "C" void kernel_launch(void* const* d_in, const int* in_sizes, int n_in,
                              void* d_out, int out_size, void* d_ws, size_t ws_size,
                              hipStream_t stream)
{
    (void)in_sizes; (void)n_in; (void)out_size; (void)ws_size;

    const float* x       = (const float*)d_in[0];
    const float* dist    = (const float*)d_in[1];
    const float* freq    = (const float*)d_in[2];
    const float* sbf     = (const float*)d_in[3];
    const int*   idx_kj  = (const int*)d_in[4];
    const int*   idx_ji  = (const int*)d_in[5];
    const int*   edge_i  = (const int*)d_in[6];
    const float* Wi_rbf1 = (const float*)d_in[8];
    const float* Wi_rbf2 = (const float*)d_in[9];
    const float* Wi_sbf1 = (const float*)d_in[10];
    const float* Wi_sbf2 = (const float*)d_in[11];
    const float* Wi_kj   = (const float*)d_in[12];
    const float* bi_kj   = (const float*)d_in[13];
    const float* Wi_ji   = (const float*)d_in[14];
    const float* bi_ji   = (const float*)d_in[15];
    const float* Wi_down = (const float*)d_in[16];
    const float* Wi_up   = (const float*)d_in[17];
    const float* Wi_res  = (const float*)d_in[18];
    const float* bi_res  = (const float*)d_in[19];
    const float* Wi_lin  = (const float*)d_in[20];
    const float* bi_lin  = (const float*)d_in[21];
    const float* Wo_rbf  = (const float*)d_in[22];
    const float* Wo_up   = (const float*)d_in[23];
    const float* bo_up   = (const float*)d_in[24];
    const float* Wo_lin  = (const float*)d_in[25];
    const float* bo_lin  = (const float*)d_in[26];
    const float* Wo_out  = (const float*)d_in[27];
    float* P = (float*)d_out;

    // ---- workspace carve-up ----
    float* w      = (float*)d_ws;
    float* rbf    = w;  w += (size_t)E * R;
    float* xeA    = w;  w += (size_t)E * H;
    float* xeB    = w;  w += (size_t)E * H;
    float* xji    = w;  w += (size_t)E * H;
    float* down   = w;  w += (size_t)E * INTD;
    float* agg    = w;  w += (size_t)E * INTD;
    float* tmp0   = w;  w += (size_t)T * BE;
    float* tmp1   = w;  w += (size_t)T * BE;
    float* nodes  = w;  w += (size_t)NN * H;
    int* ip       = (int*)w;
    int* trip_rs  = ip;  ip += E + 1;
    int* trip_cur = ip;  ip += E;
    int* rank_t   = ip;  ip += T;
    int* kjs      = ip;  ip += T;
    int* edge_rs  = ip;  ip += NN + 1;
    int* edge_cur = ip;  ip += NN;
    int* perm_e   = ip;  ip += E;
    int* bsumT    = ip;  ip += 64;
    int* bsumE    = ip;  ip += 64;

    // ---- CSR build ----
    hipMemsetAsync(trip_cur, 0, (size_t)E * sizeof(int), stream);
    hipMemsetAsync(edge_cur, 0, (size_t)NN * sizeof(int), stream);
    k_count<<<(T + 255) / 256, 256, 0, stream>>>(idx_ji, T, trip_cur);
    k_count<<<(E + 255) / 256, 256, 0, stream>>>(edge_i, E, edge_cur);
    const int nbT = (E + 2047) / 2048, nbE = (NN + 2047) / 2048;
    k_red<<<nbT, 256, 0, stream>>>(trip_cur, E, bsumT);
    k_scanb<<<1, 64, 0, stream>>>(bsumT, nbT);
    k_fill_rs<<<nbT, 256, 0, stream>>>(trip_cur, E, bsumT, trip_rs, trip_cur);
    k_red<<<nbE, 256, 0, stream>>>(edge_cur, NN, bsumE);
    k_scanb<<<1, 64, 0, stream>>>(bsumE, nbE);
    k_fill_rs<<<nbE, 256, 0, stream>>>(edge_cur, NN, bsumE, edge_rs, edge_cur);
    k_fill_trip<<<(T + 255) / 256, 256, 0, stream>>>(idx_ji, idx_kj, T, trip_cur, kjs, rank_t);
    k_fill<<<(E + 255) / 256, 256, 0, stream>>>(edge_i, E, edge_cur, perm_e);

    hipMemsetAsync(d_out, 0, (size_t)NN * sizeof(float), stream);
    k_rbf<<<(E + 255) / 256, 256, 0, stream>>>(dist, freq, rbf);
    k_sbfproj2<<<T / 32, 256, 0, stream>>>(sbf, Wi_sbf1, Wi_sbf1 + (size_t)SR * BE,
                                           rank_t, tmp0, tmp1);

    auto out_block = [&](int b, const float* xe) {
        k_nodes<<<NN / 2, 256, 0, stream>>>(edge_rs, perm_e, rbf,
                                            Wo_rbf + (size_t)b * R * H, xe, nodes);
        k_outchain<<<NN / 16, 256, 0, stream>>>(nodes,
                                                Wo_up + (size_t)b * H * OE,
                                                bo_up + (size_t)b * OE,
                                                Wo_lin + (size_t)b * 3 * OE * OE,
                                                bo_lin + (size_t)b * 3 * OE,
                                                Wo_out + (size_t)b * OE, P);
    };

    auto interact = [&](int b, const float* xe, const float* tmp, float* out) {
        k_front<<<E / 32, 256, 0, stream>>>(xe, rbf,
                                            Wi_ji + (size_t)b * H * H, bi_ji + (size_t)b * H,
                                            Wi_kj + (size_t)b * H * H, bi_kj + (size_t)b * H,
                                            Wi_rbf1 + (size_t)b * R * BE,
                                            Wi_rbf2 + (size_t)b * BE * H,
                                            Wi_down + (size_t)b * H * INTD,
                                            xji, down);
        k_agg<<<E / 4, 256, 0, stream>>>(trip_rs, kjs, tmp, down,
                                         Wi_sbf2 + (size_t)b * BE * INTD, agg);
        k_tail<<<E / 32, 256, 0, stream>>>(agg, xji, xe,
                                           Wi_up + (size_t)b * INTD * H,
                                           Wi_res + (size_t)b * 3 * 2 * H * H,
                                           bi_res + (size_t)b * 3 * 2 * H,
                                           Wi_lin + (size_t)b * H * H,
                                           bi_lin + (size_t)b * H, out);
    };

    out_block(0, x);
    interact(0, x, tmp0, xeB);
    out_block(1, xeB);
    interact(1, xeB, tmp1, xeA);
    out_block(2, xeA);
}